// Round 13
// baseline (92.554 us; speedup 1.0000x reference)
//
#include <hip/hip_runtime.h>
#include <hip/hip_bf16.h>
#include <hip/hip_fp16.h>

// LearnableGraphBuilder: fused gather + dot-score + K=20 softmax + edge emit.
// Device facts (rounds 0-12): neighbor_idx = int32; d_out = float32 flat
// [src | dst | weight] (6M floats); reference compared in bf16 domain.
// Confirmed model: main-kernel time = TCC bytes / 3.66 TB/s (random-line
// fabric rate, pinned across 6 schedule/occupancy/row-size variants);
// FETCH at compulsory floor = 8-XCD-replicated fp16 table + idx + src.
// fp16 = precision floor (bf16 fails the 2% weight threshold arithmetic).
// This round: cvt-only polish — one-shot exact grid, 16 floats/thread,
// ILP-4 NT loads. Main kernel byte-identical to round 12 (proven at floor).
constexpr int N_NODES = 100000;
constexpr int TOP_K   = 20;
constexpr int EMB_DIM = 128;
constexpr int NK      = N_NODES * TOP_K;

typedef float        nf4 __attribute__((ext_vector_type(4)));
typedef unsigned int nu4 __attribute__((ext_vector_type(4)));

__device__ __forceinline__ float bf16r(float x) {
    return __bfloat162float(__float2bfloat16(x));
}
__device__ __forceinline__ int clampN(int t) {
    return (t < 0) ? 0 : ((t >= N_NODES) ? (N_NODES - 1) : t);
}
// unpack 2 packed fp16 (in a u32) -> float2, via local copy (addressable)
__device__ __forceinline__ float2 h2f2(unsigned u) {
    __half2 h = *reinterpret_cast<__half2*>(&u);
    return __half22float2(h);
}
__device__ __forceinline__ unsigned pack2h(float a, float b) {
    const __half2 h = __floats2half2_rn(a, b);
    unsigned u;
    __builtin_memcpy(&u, &h, 4);
    return u;
}

// ---- table conversion: f32 -> fp16, one-shot, 16 elements/thread.
// 4 independent NT 16 B loads (ILP-4) + 2 NT 16 B stores per thread.
// total threads = 12.8M/16 = 800K = 3125 blocks x 256 (exact, no loop).
__global__ __launch_bounds__(256) void cvt_kernel(
    const float* __restrict__ in, __half* __restrict__ outh)
{
    const int i = blockIdx.x * blockDim.x + threadIdx.x;   // 16-float chunk id
    const nf4* p = reinterpret_cast<const nf4*>(in) + 4 * (size_t)i;
    const nf4 v0 = __builtin_nontemporal_load(p);
    const nf4 v1 = __builtin_nontemporal_load(p + 1);
    const nf4 v2 = __builtin_nontemporal_load(p + 2);
    const nf4 v3 = __builtin_nontemporal_load(p + 3);
    nu4 u0, u1;
    u0.x = pack2h(v0.x, v0.y);
    u0.y = pack2h(v0.z, v0.w);
    u0.z = pack2h(v1.x, v1.y);
    u0.w = pack2h(v1.z, v1.w);
    u1.x = pack2h(v2.x, v2.y);
    u1.y = pack2h(v2.z, v2.w);
    u1.z = pack2h(v3.x, v3.y);
    u1.w = pack2h(v3.z, v3.w);
    nu4* q = reinterpret_cast<nu4*>(outh) + 2 * (size_t)i;
    __builtin_nontemporal_store(u0, q);
    __builtin_nontemporal_store(u1, q + 1);
}

// ---- main kernel: both operands from the fp16 table (round-12, at floor) --
// One 64-lane wave per node. 4 groups x 16 lanes; group g handles neighbor
// k = 4*it + g. Lane gl owns elements [8gl, 8gl+8): one 16 B load per row
// -> a 16-lane group covers the whole 256 B fp16 row.
__global__ __launch_bounds__(256) void lgb_fp16(
    const __half* __restrict__ embh,
    const int*   __restrict__ nidx,
    float* __restrict__ out)
{
    const int wid  = blockIdx.x * 4 + (threadIdx.x >> 6);
    if (wid >= N_NODES) return;
    const int lane = threadIdx.x & 63;
    const int g    = (lane >> 4) & 3;
    const int gl   = lane & 15;
    const int n    = wid;

    int idxv = (lane < TOP_K)
        ? __builtin_nontemporal_load(nidx + n * TOP_K + lane) : 0;
    idxv = clampN(idxv);

    // source row (sequential; plain load -> warms L2 with table lines)
    const nu4 qe = reinterpret_cast<const nu4*>(embh + (size_t)n * EMB_DIM)[gl];
    const float2 e0 = h2f2(qe.x);
    const float2 e1 = h2f2(qe.y);
    const float2 e2 = h2f2(qe.z);
    const float2 e3 = h2f2(qe.w);

    float pk[5];
    #pragma unroll
    for (int it = 0; it < 5; ++it) {
        const int nb = __shfl(idxv, it * 4 + g);
        const nu4 q = reinterpret_cast<const nu4*>(embh + (size_t)nb * EMB_DIM)[gl];
        const float2 f0 = h2f2(q.x);
        const float2 f1 = h2f2(q.y);
        const float2 f2 = h2f2(q.z);
        const float2 f3 = h2f2(q.w);
        float p = e0.x*f0.x + e0.y*f0.y + e1.x*f1.x + e1.y*f1.y
                + e2.x*f2.x + e2.y*f2.y + e3.x*f3.x + e3.y*f3.y;
        p += __shfl_xor(p, 1);
        p += __shfl_xor(p, 2);
        p += __shfl_xor(p, 4);
        p += __shfl_xor(p, 8);
        pk[it] = p;
    }

    float m = fmaxf(fmaxf(fmaxf(pk[0], pk[1]), fmaxf(pk[2], pk[3])), pk[4]);
    m = fmaxf(m, __shfl_xor(m, 16));
    m = fmaxf(m, __shfl_xor(m, 32));

    float ex[5];
    float s = 0.f;
    #pragma unroll
    for (int it = 0; it < 5; ++it) {
        ex[it] = __expf(pk[it] - m);
        s += ex[it];
    }
    s += __shfl_xor(s, 16);
    s += __shfl_xor(s, 32);
    const float inv = 1.0f / s;

    // outputs: plain write-back stores (L2 coalesces partial lines)
    if (lane < TOP_K) {
        const int pos = n * TOP_K + lane;
        out[pos]      = bf16r((float)n);      // src row
        out[NK + pos] = bf16r((float)idxv);   // dst row
    }
    if (gl == 0) {
        #pragma unroll
        for (int it = 0; it < 5; ++it) {
            const int pos = n * TOP_K + it * 4 + g;
            out[2 * NK + pos] = bf16r(ex[it] * inv);   // weight
        }
    }
}

// ---- fallback: f32 gather (round-4 proven kernel), if d_ws too small ----
__global__ __launch_bounds__(256) void lgb_f32(
    const float* __restrict__ emb,
    const int*   __restrict__ nidx,
    float* __restrict__ out)
{
    const int wid  = blockIdx.x * 4 + (threadIdx.x >> 6);
    if (wid >= N_NODES) return;
    const int lane = threadIdx.x & 63;
    const int g    = (lane >> 4) & 3;
    const int gl   = lane & 15;
    const int n    = wid;

    int idxv = (lane < TOP_K) ? nidx[n * TOP_K + lane] : 0;
    idxv = clampN(idxv);

    const float4* erow = reinterpret_cast<const float4*>(emb + (size_t)n * EMB_DIM);
    const float4 e0 = erow[gl];
    const float4 e1 = erow[gl + 16];

    float pk[5];
    #pragma unroll
    for (int it = 0; it < 5; ++it) {
        const int nb = __shfl(idxv, it * 4 + g);
        const float4* brow = reinterpret_cast<const float4*>(emb + (size_t)nb * EMB_DIM);
        const float4 b0 = brow[gl];
        const float4 b1 = brow[gl + 16];
        float p = e0.x*b0.x + e0.y*b0.y + e0.z*b0.z + e0.w*b0.w
                + e1.x*b1.x + e1.y*b1.y + e1.z*b1.z + e1.w*b1.w;
        p += __shfl_xor(p, 1);
        p += __shfl_xor(p, 2);
        p += __shfl_xor(p, 4);
        p += __shfl_xor(p, 8);
        pk[it] = p;
    }

    float m = fmaxf(fmaxf(fmaxf(pk[0], pk[1]), fmaxf(pk[2], pk[3])), pk[4]);
    m = fmaxf(m, __shfl_xor(m, 16));
    m = fmaxf(m, __shfl_xor(m, 32));

    float ex[5];
    float s = 0.f;
    #pragma unroll
    for (int it = 0; it < 5; ++it) {
        ex[it] = __expf(pk[it] - m);
        s += ex[it];
    }
    s += __shfl_xor(s, 16);
    s += __shfl_xor(s, 32);
    const float inv = 1.0f / s;

    if (lane < TOP_K) {
        const int pos = n * TOP_K + lane;
        out[pos]      = bf16r((float)n);
        out[NK + pos] = bf16r((float)idxv);
    }
    if (gl == 0) {
        #pragma unroll
        for (int it = 0; it < 5; ++it) {
            const int pos = n * TOP_K + it * 4 + g;
            out[2 * NK + pos] = bf16r(ex[it] * inv);
        }
    }
}

extern "C" void kernel_launch(void* const* d_in, const int* in_sizes, int n_in,
                              void* d_out, int out_size, void* d_ws, size_t ws_size,
                              hipStream_t stream) {
    const float* emb = (const float*)d_in[0];
    const int* nidx = (const int*)d_in[1];
    float* out = (float*)d_out;
    const int blocks = (N_NODES + 3) / 4;   // 4 waves (nodes) per 256-thread block

    const size_t need = (size_t)N_NODES * EMB_DIM * sizeof(__half);  // 25.6 MB
    if (ws_size >= need) {
        __half* embh = (__half*)d_ws;
        // 12.8M floats / 16 per thread = 800K threads (exact)
        const int cvt_blocks = (N_NODES * EMB_DIM / 16) / 256;  // 3125
        cvt_kernel<<<cvt_blocks, 256, 0, stream>>>(emb, embh);
        lgb_fp16<<<blocks, 256, 0, stream>>>(embh, nidx, out);
    } else {
        lgb_f32<<<blocks, 256, 0, stream>>>(emb, nidx, out);
    }
}

// Round 14
// 84.561 us; speedup vs baseline: 1.0945x; 1.0945x over previous
//
#include <hip/hip_runtime.h>
#include <hip/hip_bf16.h>
#include <hip/hip_fp16.h>

// LearnableGraphBuilder: fused gather + dot-score + K=20 softmax + edge emit.
// Device facts (rounds 0-13): neighbor_idx = int32; d_out = float32 flat
// [src | dst | weight] (6M floats); reference compared in bf16 domain.
// Confirmed model: main-kernel time = TCC bytes / 3.62 TB/s (random-line
// fabric rate, pinned across 6 schedule/occupancy/row-size variants);
// FETCH at compulsory floor = 8-XCD-replicated fp16 table + idx + src.
// fp16 = precision floor (bf16 fails the 2% weight threshold arithmetic).
// Round-13 lesson: cvt is fastest with 16 B/thread fully lane-coalesced
// plain loads/stores (round-8 form, 14.7 us); fatter per-thread chunks
// break inter-lane coalescing and NT stores inflate write traffic.
constexpr int N_NODES = 100000;
constexpr int TOP_K   = 20;
constexpr int EMB_DIM = 128;
constexpr int NK      = N_NODES * TOP_K;

typedef unsigned int nu4 __attribute__((ext_vector_type(4)));

__device__ __forceinline__ float bf16r(float x) {
    return __bfloat162float(__float2bfloat16(x));
}
__device__ __forceinline__ int clampN(int t) {
    return (t < 0) ? 0 : ((t >= N_NODES) ? (N_NODES - 1) : t);
}
// unpack 2 packed fp16 (in a u32) -> float2, via local copy (addressable)
__device__ __forceinline__ float2 h2f2(unsigned u) {
    __half2 h = *reinterpret_cast<__half2*>(&u);
    return __half22float2(h);
}

// ---- table conversion: f32 -> fp16, 4 elements/thread, grid-stride,
// fully lane-coalesced 16 B loads / 8 B stores (round-8 proven fastest) ----
__global__ __launch_bounds__(256) void cvt_kernel(
    const float* __restrict__ in, __half* __restrict__ outh)
{
    const int total = N_NODES * EMB_DIM / 4;   // 3.2M float4 groups
    for (int i = blockIdx.x * blockDim.x + threadIdx.x; i < total;
         i += gridDim.x * blockDim.x) {
        const float4 v = reinterpret_cast<const float4*>(in)[i];
        const __half2 h0 = __floats2half2_rn(v.x, v.y);
        const __half2 h1 = __floats2half2_rn(v.z, v.w);
        uint2 u;
        __builtin_memcpy(&u.x, &h0, 4);
        __builtin_memcpy(&u.y, &h1, 4);
        reinterpret_cast<uint2*>(outh)[i] = u;
    }
}

// ---- main kernel: both operands from the fp16 table (round-12, at floor) --
// One 64-lane wave per node. 4 groups x 16 lanes; group g handles neighbor
// k = 4*it + g. Lane gl owns elements [8gl, 8gl+8): one 16 B load per row
// -> a 16-lane group covers the whole 256 B fp16 row.
__global__ __launch_bounds__(256) void lgb_fp16(
    const __half* __restrict__ embh,
    const int*   __restrict__ nidx,
    float* __restrict__ out)
{
    const int wid  = blockIdx.x * 4 + (threadIdx.x >> 6);
    if (wid >= N_NODES) return;
    const int lane = threadIdx.x & 63;
    const int g    = (lane >> 4) & 3;
    const int gl   = lane & 15;
    const int n    = wid;

    int idxv = (lane < TOP_K)
        ? __builtin_nontemporal_load(nidx + n * TOP_K + lane) : 0;
    idxv = clampN(idxv);

    // source row (sequential; plain load -> warms L2 with table lines)
    const nu4 qe = reinterpret_cast<const nu4*>(embh + (size_t)n * EMB_DIM)[gl];
    const float2 e0 = h2f2(qe.x);
    const float2 e1 = h2f2(qe.y);
    const float2 e2 = h2f2(qe.z);
    const float2 e3 = h2f2(qe.w);

    float pk[5];
    #pragma unroll
    for (int it = 0; it < 5; ++it) {
        const int nb = __shfl(idxv, it * 4 + g);
        const nu4 q = reinterpret_cast<const nu4*>(embh + (size_t)nb * EMB_DIM)[gl];
        const float2 f0 = h2f2(q.x);
        const float2 f1 = h2f2(q.y);
        const float2 f2 = h2f2(q.z);
        const float2 f3 = h2f2(q.w);
        float p = e0.x*f0.x + e0.y*f0.y + e1.x*f1.x + e1.y*f1.y
                + e2.x*f2.x + e2.y*f2.y + e3.x*f3.x + e3.y*f3.y;
        p += __shfl_xor(p, 1);
        p += __shfl_xor(p, 2);
        p += __shfl_xor(p, 4);
        p += __shfl_xor(p, 8);
        pk[it] = p;
    }

    float m = fmaxf(fmaxf(fmaxf(pk[0], pk[1]), fmaxf(pk[2], pk[3])), pk[4]);
    m = fmaxf(m, __shfl_xor(m, 16));
    m = fmaxf(m, __shfl_xor(m, 32));

    float ex[5];
    float s = 0.f;
    #pragma unroll
    for (int it = 0; it < 5; ++it) {
        ex[it] = __expf(pk[it] - m);
        s += ex[it];
    }
    s += __shfl_xor(s, 16);
    s += __shfl_xor(s, 32);
    const float inv = 1.0f / s;

    // outputs: plain write-back stores (L2 coalesces partial lines)
    if (lane < TOP_K) {
        const int pos = n * TOP_K + lane;
        out[pos]      = bf16r((float)n);      // src row
        out[NK + pos] = bf16r((float)idxv);   // dst row
    }
    if (gl == 0) {
        #pragma unroll
        for (int it = 0; it < 5; ++it) {
            const int pos = n * TOP_K + it * 4 + g;
            out[2 * NK + pos] = bf16r(ex[it] * inv);   // weight
        }
    }
}

// ---- fallback: f32 gather (round-4 proven kernel), if d_ws too small ----
__global__ __launch_bounds__(256) void lgb_f32(
    const float* __restrict__ emb,
    const int*   __restrict__ nidx,
    float* __restrict__ out)
{
    const int wid  = blockIdx.x * 4 + (threadIdx.x >> 6);
    if (wid >= N_NODES) return;
    const int lane = threadIdx.x & 63;
    const int g    = (lane >> 4) & 3;
    const int gl   = lane & 15;
    const int n    = wid;

    int idxv = (lane < TOP_K) ? nidx[n * TOP_K + lane] : 0;
    idxv = clampN(idxv);

    const float4* erow = reinterpret_cast<const float4*>(emb + (size_t)n * EMB_DIM);
    const float4 e0 = erow[gl];
    const float4 e1 = erow[gl + 16];

    float pk[5];
    #pragma unroll
    for (int it = 0; it < 5; ++it) {
        const int nb = __shfl(idxv, it * 4 + g);
        const float4* brow = reinterpret_cast<const float4*>(emb + (size_t)nb * EMB_DIM);
        const float4 b0 = brow[gl];
        const float4 b1 = brow[gl + 16];
        float p = e0.x*b0.x + e0.y*b0.y + e0.z*b0.z + e0.w*b0.w
                + e1.x*b1.x + e1.y*b1.y + e1.z*b1.z + e1.w*b1.w;
        p += __shfl_xor(p, 1);
        p += __shfl_xor(p, 2);
        p += __shfl_xor(p, 4);
        p += __shfl_xor(p, 8);
        pk[it] = p;
    }

    float m = fmaxf(fmaxf(fmaxf(pk[0], pk[1]), fmaxf(pk[2], pk[3])), pk[4]);
    m = fmaxf(m, __shfl_xor(m, 16));
    m = fmaxf(m, __shfl_xor(m, 32));

    float ex[5];
    float s = 0.f;
    #pragma unroll
    for (int it = 0; it < 5; ++it) {
        ex[it] = __expf(pk[it] - m);
        s += ex[it];
    }
    s += __shfl_xor(s, 16);
    s += __shfl_xor(s, 32);
    const float inv = 1.0f / s;

    if (lane < TOP_K) {
        const int pos = n * TOP_K + lane;
        out[pos]      = bf16r((float)n);
        out[NK + pos] = bf16r((float)idxv);
    }
    if (gl == 0) {
        #pragma unroll
        for (int it = 0; it < 5; ++it) {
            const int pos = n * TOP_K + it * 4 + g;
            out[2 * NK + pos] = bf16r(ex[it] * inv);
        }
    }
}

extern "C" void kernel_launch(void* const* d_in, const int* in_sizes, int n_in,
                              void* d_out, int out_size, void* d_ws, size_t ws_size,
                              hipStream_t stream) {
    const float* emb = (const float*)d_in[0];
    const int* nidx = (const int*)d_in[1];
    float* out = (float*)d_out;
    const int blocks = (N_NODES + 3) / 4;   // 4 waves (nodes) per 256-thread block

    const size_t need = (size_t)N_NODES * EMB_DIM * sizeof(__half);  // 25.6 MB
    if (ws_size >= need) {
        __half* embh = (__half*)d_ws;
        cvt_kernel<<<2048, 256, 0, stream>>>(emb, embh);
        lgb_fp16<<<blocks, 256, 0, stream>>>(embh, nidx, out);
    } else {
        lgb_f32<<<blocks, 256, 0, stream>>>(emb, nidx, out);
    }
}